// Round 1
// baseline (15.279 us; speedup 1.0000x reference)
//
#include <hip/hip_runtime.h>
#include <math.h>

// Multi-scale glimpse sensor.
// img: (B, 224, 224, 3) f32, loc: (B, 2) f32 in [-1, 1]
// out: (B, 3, 16, 16, 3) f32
//
// Semantics matched to JAX reference:
//  - cy = clip(floor((loc0+1)*0.5*H), 0, H), cx likewise with W
//  - scale i: patch side d = 16<<i centered so top-left = (cy - d/2, cx - d/2)
//    in ORIGINAL image coords; out-of-image taps contribute 0 (zero pad).
//  - jax.image.resize bilinear with antialias=True (default):
//    stride s = d/16, T = 2s taps, base weight 1 - |t-(T-1)/2|/s,
//    normalized over taps valid within the PATCH [0, d) per axis.
//    d=16 => identity.

#define IMG_H 224
#define IMG_W 224
#define IMG_C 3
#define GW    16
#define KSC   3

template <int STRIDE>
__device__ inline void glimpse_accum(const float* __restrict__ img, int b,
                                     int oy0, int ox0, int jy, int jx,
                                     float acc[3]) {
  constexpr int T = STRIDE * 2;            // taps per axis
  constexpr int D = GW * STRIDE;           // patch side
  constexpr float INV_KS = 1.0f / (float)STRIDE;
  constexpr float CTR = 0.5f * (float)(T - 1);

  const int ky0 = STRIDE * jy - (STRIDE / 2);  // first tap, patch coords
  const int kx0 = STRIDE * jx - (STRIDE / 2);

  float wy[T], wx[T];
  float sy = 0.f, sx = 0.f;
#pragma unroll
  for (int t = 0; t < T; ++t) {
    const float wb = 1.0f - fabsf((float)t - CTR) * INV_KS;
    const int ky = ky0 + t;
    const int kx = kx0 + t;
    wy[t] = (ky >= 0 && ky < D) ? wb : 0.f;
    wx[t] = (kx >= 0 && kx < D) ? wb : 0.f;
    sy += wy[t];
    sx += wx[t];
  }
  const float inv_norm = 1.0f / (sy * sx);

  float a0 = 0.f, a1 = 0.f, a2 = 0.f;
#pragma unroll
  for (int ty = 0; ty < T; ++ty) {
    const int yy = oy0 + ky0 + ty;         // original-image row
    if (wy[ty] == 0.f || yy < 0 || yy >= IMG_H) continue;
    float r0 = 0.f, r1 = 0.f, r2 = 0.f;
    const float* rowp = img + ((size_t)b * IMG_H + yy) * (IMG_W * IMG_C);
#pragma unroll
    for (int tx = 0; tx < T; ++tx) {
      const int xx = ox0 + kx0 + tx;       // original-image col
      if (wx[tx] == 0.f || xx < 0 || xx >= IMG_W) continue;
      const float* p = rowp + (size_t)xx * IMG_C;
      r0 += wx[tx] * p[0];
      r1 += wx[tx] * p[1];
      r2 += wx[tx] * p[2];
    }
    a0 += wy[ty] * r0;
    a1 += wy[ty] * r1;
    a2 += wy[ty] * r2;
  }
  acc[0] = a0 * inv_norm;
  acc[1] = a1 * inv_norm;
  acc[2] = a2 * inv_norm;
}

__global__ __launch_bounds__(256) void glimpse_kernel(
    const float* __restrict__ img, const float* __restrict__ loc,
    float* __restrict__ out) {
  const int blk = blockIdx.x;      // b * KSC + scale
  const int b = blk / KSC;
  const int sc = blk % KSC;        // block-uniform => no divergence
  const int tid = threadIdx.x;     // 0..255
  const int jy = tid >> 4;
  const int jx = tid & 15;

  const float ly = loc[b * 2 + 0];
  const float lx = loc[b * 2 + 1];
  int cy = (int)floorf((ly + 1.0f) * 0.5f * (float)IMG_H);
  int cx = (int)floorf((lx + 1.0f) * 0.5f * (float)IMG_W);
  cy = min(max(cy, 0), IMG_H);
  cx = min(max(cx, 0), IMG_W);

  const int d = GW << sc;
  const int half = d >> 1;
  const int oy0 = cy - half;       // patch top-left in original image coords
  const int ox0 = cx - half;

  float acc[3] = {0.f, 0.f, 0.f};

  if (sc == 0) {
    // d == 16: resize is identity; just a (possibly zero-padded) gather.
    const int yy = oy0 + jy;
    const int xx = ox0 + jx;
    if (yy >= 0 && yy < IMG_H && xx >= 0 && xx < IMG_W) {
      const float* p = img + (((size_t)b * IMG_H + yy) * IMG_W + xx) * IMG_C;
      acc[0] = p[0];
      acc[1] = p[1];
      acc[2] = p[2];
    }
  } else if (sc == 1) {
    glimpse_accum<2>(img, b, oy0, ox0, jy, jx, acc);
  } else {
    glimpse_accum<4>(img, b, oy0, ox0, jy, jx, acc);
  }

  // out layout: (B, K, 16, 16, C); tid == jy*16+jx
  float* o = out + ((size_t)blk * 256 + tid) * 3;
  o[0] = acc[0];
  o[1] = acc[1];
  o[2] = acc[2];
}

extern "C" void kernel_launch(void* const* d_in, const int* in_sizes, int n_in,
                              void* d_out, int out_size, void* d_ws, size_t ws_size,
                              hipStream_t stream) {
  const float* img = (const float*)d_in[0];
  const float* loc = (const float*)d_in[1];
  float* out = (float*)d_out;
  const int B = in_sizes[1] / 2;   // loc is (B, 2)
  glimpse_kernel<<<B * KSC, 256, 0, stream>>>(img, loc, out);
}